// Round 13
// baseline (657.897 us; speedup 1.0000x reference)
//
#include <hip/hip_runtime.h>
#include <hip/hip_bf16.h>

#define T_DIM 8192
#define H_DIM 2048
#define F_DIM 5632

typedef __attribute__((ext_vector_type(4)))  float f32x4;
typedef __attribute__((ext_vector_type(16))) float f32x16;
typedef __attribute__((ext_vector_type(8)))  short bf16x8;

static __device__ __forceinline__ void gload16(const void* g, void* l) {
    __builtin_amdgcn_global_load_lds(
        (const __attribute__((address_space(1))) void*)g,
        (__attribute__((address_space(3))) void*)l,
        16, 0, 0);
}

static __device__ __forceinline__ unsigned short f2bf(float f) {
    unsigned int u = __float_as_uint(f);
    u += 0x7fffu + ((u >> 16) & 1u);
    return (unsigned short)(u >> 16);
}

// ---- f32 -> bf16 conversion: X ----
__global__ __launch_bounds__(256)
void cvt_x(const float* __restrict__ src, unsigned short* __restrict__ dst, long n)
{
    const long stride = (long)gridDim.x * blockDim.x;
    for (long i = (long)blockIdx.x * blockDim.x + threadIdx.x; i * 4 < n; i += stride) {
        const float4 v = *(const float4*)(src + i * 4);
        ushort4 o;
        o.x = f2bf(v.x); o.y = f2bf(v.y); o.z = f2bf(v.z); o.w = f2bf(v.w);
        *(ushort4*)(dst + i * 4) = o;
    }
}

// ---- f32 -> bf16 weight conversion.
// W1/W2 interleaved into W12[11264 x 2048] at 32-row granularity:
//   W1 row r -> R = (r>>5)*64 + (r&31);  W2 row r -> R + 32
// so W12 rows [64g..64g+32) = gate cols [32g..32g+32), [64g+32..64g+64) = up
// of the SAME cols. W3 converted linearly.
__global__ __launch_bounds__(256)
void cvt_w(const float* __restrict__ w1, const float* __restrict__ w2,
           const float* __restrict__ w3, const int* __restrict__ eidx,
           unsigned short* __restrict__ W12, unsigned short* __restrict__ W3b)
{
    const long seg = (long)F_DIM * H_DIM;
    const long e   = (long)(*eidx);
    const long nchunks = 3 * seg / 4;
    const long stride = (long)gridDim.x * blockDim.x;
    for (long i = (long)blockIdx.x * blockDim.x + threadIdx.x; i < nchunks; i += stride) {
        const long t = i * 4;
        const int  s = (int)(t / seg);
        const long o = t - (long)s * seg;
        const float4 v = *(const float4*)((s == 0 ? w1 : s == 1 ? w2 : w3) + e * seg + o);
        ushort4 ov;
        ov.x = f2bf(v.x); ov.y = f2bf(v.y); ov.z = f2bf(v.z); ov.w = f2bf(v.w);
        if (s == 2) {
            *(ushort4*)(W3b + o) = ov;
        } else {
            const long r   = o >> 11;
            const long col = o & 2047;
            const long R   = (r >> 5) * 64 + (r & 31) + (s == 1 ? 32 : 0);
            *(ushort4*)(W12 + R * 2048 + col) = ov;
        }
    }
}

// ---- staging / frag helpers (XOR-swizzled, rule #21) ----
static __device__ __forceinline__ void stage_half(const unsigned short* __restrict__ g,
                                                  long grow0, long ldk, long kb,
                                                  unsigned short* l, int t, int i0)
{
    const int r  = t >> 3;
    const int cc = ((t & 7) ^ (r & 7)) << 3;   // inverse-swizzled source column
    #pragma unroll
    for (int ii = i0; ii < i0 + 2; ++ii)
        gload16(g + (grow0 + ii * 64 + r) * ldk + kb + cc,
                l + ii * 4096 + t * 8);
}

// generalized: chunk c in 0..7 (16B units within the 64-elem row)
static __device__ __forceinline__ bf16x8 ldsfragc(const unsigned short* base,
                                                  int row, int c)
{
    return *(const bf16x8*)(base + row * 64 + ((c ^ (row & 7)) << 3));
}

static __device__ __forceinline__ bf16x8 ldsfrag(const unsigned short* base,
                                                 int row, int kk, int q)
{
    return ldsfragc(base, row, kk * 4 + q);
}

// ---- FC1 (32x32x16 MFMA): tile 256 M x 64 out-cols, B-tile 128 W12 rows.
// 8 waves = 4M x 2N; per wave Mf=2 (32-row) x Nf=2 (gate,up) x 4 K-slices
// = 16 MFMA(32x32x16)/iter (same FLOP as r10's 32x 16x16, half the instrs,
// +15% pipe ceiling m119). LDS 80 KB (A dbuf 2x32KB + B single 16KB)
// -> 2 blocks/CU. Same vmcnt(4) ledger and barrier discipline as r10.
__global__ __launch_bounds__(512, 4)
void gemm_fc1(const unsigned short* __restrict__ X,
              const unsigned short* __restrict__ W12,
              unsigned short* __restrict__ Hout)
{
    constexpr int NK = H_DIM / 64;   // 32

    __shared__ __align__(16) unsigned short sAll[40960];  // 80 KiB

    const int tid  = threadIdx.x;
    const int lane = tid & 63;
    const int wid  = tid >> 6;
    const int wm   = wid >> 1;       // 0..3 : 64-row M groups
    const int wn   = wid & 1;        // 0..1 : 32-col N groups
    const int l5   = lane & 31;
    const int h    = lane >> 5;      // K-half selector

    // grid 2816 = 8 XCD x 352; per XCD: bn-major quads of bm (r10 map)
    const int bid = blockIdx.x;
    const int x   = bid & 7;
    const int ii  = bid >> 3;        // 0..351
    const int bn  = ii >> 2;         // 0..87
    const int bm  = x * 4 + (ii & 3);// 0..31

    const long arow0 = (long)bm * 256;
    const long brow0 = (long)bn * 128;   // W12 rows

    unsigned short* sB = sAll + 32768;   // 16 KB single-buffered B

    f32x16 acc[2][2] = {};               // [mi][nf]  nf0=gate nf1=up

    // prologue: A(0) -> bufA0 (4 issues); B(0) -> sB (2 issues)
    stage_half(X,   arow0, H_DIM, 0, sAll, tid, 0);
    stage_half(X,   arow0, H_DIM, 0, sAll, tid, 2);
    stage_half(W12, brow0, H_DIM, 0, sB,   tid, 0);

    for (int j = 0; j < NK; ++j) {
        unsigned short* la = sAll + (j & 1) * 16384;

        if (j + 1 < NK) {
            unsigned short* na = sAll + ((j + 1) & 1) * 16384;
            stage_half(X, arow0, H_DIM, (long)(j + 1) * 64, na, tid, 0);
            stage_half(X, arow0, H_DIM, (long)(j + 1) * 64, na, tid, 2);
            // queue: [A(j):4, B(j):2, A(j+1):4] -> keep 4 newest
            asm volatile("s_waitcnt vmcnt(4)" ::: "memory");
        } else {
            asm volatile("s_waitcnt vmcnt(0)" ::: "memory");
        }
        __builtin_amdgcn_s_barrier();        // TOP: A(j),B(j) visible

        // hoist all B frags: row = wn*64 + nf*32 + l5, chunk = s*2 + h
        bf16x8 bf[2][4];
        #pragma unroll
        for (int nf = 0; nf < 2; ++nf)
            #pragma unroll
            for (int s = 0; s < 4; ++s)
                bf[nf][s] = ldsfragc(sB, wn * 64 + nf * 32 + l5, s * 2 + h);

        // ---- phase 0: mi = 0 ----
        {
            bf16x8 af[4];
            #pragma unroll
            for (int s = 0; s < 4; ++s)
                af[s] = ldsfragc(la, wm * 64 + l5, s * 2 + h);
            __builtin_amdgcn_s_barrier();
            __builtin_amdgcn_s_setprio(1);
            #pragma unroll
            for (int nf = 0; nf < 2; ++nf)
                #pragma unroll
                for (int s = 0; s < 4; ++s)
                    acc[0][nf] = __builtin_amdgcn_mfma_f32_32x32x16_bf16(
                        af[s], bf[nf][s], acc[0][nf], 0, 0, 0);
            __builtin_amdgcn_s_setprio(0);
            __builtin_amdgcn_s_barrier();
        }

        // ---- phase 1: mi = 1 (+ stage B(j+1) into sB, 2 issues) ----
        {
            bf16x8 af[4];
            #pragma unroll
            for (int s = 0; s < 4; ++s)
                af[s] = ldsfragc(la, wm * 64 + 32 + l5, s * 2 + h);
            if (j + 1 < NK)
                stage_half(W12, brow0, H_DIM, (long)(j + 1) * 64, sB, tid, 0);
            __builtin_amdgcn_s_barrier();
            __builtin_amdgcn_s_setprio(1);
            #pragma unroll
            for (int nf = 0; nf < 2; ++nf)
                #pragma unroll
                for (int s = 0; s < 4; ++s)
                    acc[1][nf] = __builtin_amdgcn_mfma_f32_32x32x16_bf16(
                        af[s], bf[nf][s], acc[1][nf], 0, 0, 0);
            __builtin_amdgcn_s_setprio(0);
            __builtin_amdgcn_s_barrier();
        }
    }

    // terminal epilogue. C/D 32x32 layout (m74/m101): col = lane&31,
    // row = (reg&3) + 8*(reg>>2) + 4*(lane>>5).
    const long col = (long)bn * 64 + wn * 32 + l5;
    #pragma unroll
    for (int mi = 0; mi < 2; ++mi) {
        const long rowb = (long)bm * 256 + wm * 64 + mi * 32 + 4 * h;
        #pragma unroll
        for (int reg = 0; reg < 16; ++reg) {
            const long row = rowb + (reg & 3) + 8 * (reg >> 2);
            const float g = acc[mi][0][reg];
            const float u = acc[mi][1][reg];
            const float hv = __fdividef(g, 1.0f + __expf(-g)) * u;
            Hout[row * (long)F_DIM + col] = f2bf(hv);
        }
    }
}

// ---- GEMM2 phase (unchanged proven template) ----
#define PHASE_BODY(p, STAGE_STMT)                                              \
    {                                                                          \
        bf16x8 af[2][2];                                                       \
        _Pragma("unroll")                                                      \
        for (int l_ = 0; l_ < 2; ++l_)                                         \
            _Pragma("unroll")                                                  \
            for (int kk = 0; kk < 2; ++kk)                                     \
                af[l_][kk] = ldsfrag(la, wm * 128 + (p) * 32 + l_ * 16 + lr, kk, q); \
        STAGE_STMT;                                                            \
        __builtin_amdgcn_s_barrier();                                          \
        __builtin_amdgcn_s_setprio(1);                                         \
        _Pragma("unroll")                                                      \
        for (int l_ = 0; l_ < 2; ++l_)                                         \
            _Pragma("unroll")                                                  \
            for (int ni = 0; ni < 4; ++ni)                                     \
                _Pragma("unroll")                                              \
                for (int kk = 0; kk < 2; ++kk)                                 \
                    acc[(p) * 2 + l_][ni] = __builtin_amdgcn_mfma_f32_16x16x32_bf16( \
                        af[l_][kk], bf[ni][kk], acc[(p) * 2 + l_][ni], 0, 0, 0);     \
        __builtin_amdgcn_s_setprio(0);                                         \
        __builtin_amdgcn_s_barrier();                                          \
    }

// ---- GEMM2: Out = H * W3^T.  H [T,F] bf16, W3 [H,F] bf16, Out [T,H] f32 ----
__global__ __launch_bounds__(512, 2)
void gemm_out(const unsigned short* __restrict__ A,
              const unsigned short* __restrict__ B,
              float* __restrict__ Out)
{
    constexpr int NK  = F_DIM / 64;   // 88
    constexpr int NBN = H_DIM / 256;  // 8

    __shared__ __align__(16) unsigned short sAll[4 * 16384];

    const int tid  = threadIdx.x;
    const int lane = tid & 63;
    const int wid  = tid >> 6;
    const int wm   = wid >> 2;
    const int wn   = wid & 3;
    const int q    = lane >> 4;
    const int lr   = lane & 15;

    const int nwg = gridDim.x;                 // 256
    const int bid = blockIdx.x;
    const int cpx = nwg >> 3;
    const int swz = (bid & 7) * cpx + (bid >> 3);
    const int bm  = swz / NBN;
    const int bn  = swz % NBN;

    const long arow0 = (long)bm * 256;
    const long brow0 = (long)bn * 256;

    f32x4 acc[8][4] = {};

    stage_half(A, arow0, F_DIM, 0,  sAll,          tid, 0);
    stage_half(A, arow0, F_DIM, 0,  sAll,          tid, 2);
    stage_half(B, brow0, F_DIM, 0,  sAll + 16384,  tid, 0);
    stage_half(B, brow0, F_DIM, 0,  sAll + 16384,  tid, 2);
    stage_half(B, brow0, F_DIM, 64, sAll + 49152,  tid, 0);
    stage_half(B, brow0, F_DIM, 64, sAll + 49152,  tid, 2);

    for (int j = 0; j < NK; ++j) {
        unsigned short* la = sAll + (j & 1) * 32768;
        unsigned short* lb = la + 16384;

        if (j + 1 < NK) {
            unsigned short* na = sAll + ((j + 1) & 1) * 32768;
            stage_half(A, arow0, F_DIM, (long)(j + 1) * 64, na, tid, 0);
            stage_half(A, arow0, F_DIM, (long)(j + 1) * 64, na, tid, 2);
            asm volatile("s_waitcnt vmcnt(8)" ::: "memory");
        } else {
            asm volatile("s_waitcnt vmcnt(0)" ::: "memory");
        }
        __builtin_amdgcn_s_barrier();

        bf16x8 bf[4][2];
        #pragma unroll
        for (int ni = 0; ni < 4; ++ni)
            #pragma unroll
            for (int kk = 0; kk < 2; ++kk)
                bf[ni][kk] = ldsfrag(lb, wn * 64 + ni * 16 + lr, kk, q);

        PHASE_BODY(0, {})
        PHASE_BODY(1, { if (j + 2 < NK) stage_half(B, brow0, F_DIM, (long)(j + 2) * 64, lb, tid, 0); })
        PHASE_BODY(2, { if (j + 2 < NK) stage_half(B, brow0, F_DIM, (long)(j + 2) * 64, lb, tid, 2); })
        PHASE_BODY(3, {})
    }

    const long orow = (long)bm * 256 + wm * 128;
    const long ocol = (long)bn * 256 + wn * 64;
    #pragma unroll
    for (int mi = 0; mi < 8; ++mi)
        #pragma unroll
        for (int ni = 0; ni < 4; ++ni)
            #pragma unroll
            for (int r = 0; r < 4; ++r)
                Out[(orow + mi * 16 + q * 4 + r) * (long)H_DIM + (ocol + ni * 16 + lr)]
                    = acc[mi][ni][r];
}

extern "C" void kernel_launch(void* const* d_in, const int* in_sizes, int n_in,
                              void* d_out, int out_size, void* d_ws, size_t ws_size,
                              hipStream_t stream)
{
    const int*   eidx = (const int*)d_in[0];
    const float* x    = (const float*)d_in[1];
    const float* w1   = (const float*)d_in[2];
    const float* w2   = (const float*)d_in[3];
    const float* w3   = (const float*)d_in[4];
    float* out = (float*)d_out;

    const size_t SZ_X = (size_t)T_DIM * H_DIM;
    const size_t SZ_W = (size_t)F_DIM * H_DIM;

    unsigned short* Xb  = (unsigned short*)d_ws;
    unsigned short* W12 = Xb  + SZ_X;            // [11264 x 2048] interleaved
    unsigned short* W3b = W12 + 2 * SZ_W;
    unsigned short* Hb  = W3b + SZ_W;

    cvt_x<<<2048, 256, 0, stream>>>(x, Xb, (long)SZ_X);
    cvt_w<<<2048, 256, 0, stream>>>(w1, w2, w3, eidx, W12, W3b);

    gemm_fc1<<<2816, 512, 0, stream>>>(Xb, W12, Hb);
    gemm_out<<<(T_DIM / 256) * (H_DIM / 256), 512, 0, stream>>>(Hb, W3b, out);
}

// Round 14
// 565.524 us; speedup vs baseline: 1.1633x; 1.1633x over previous
//
#include <hip/hip_runtime.h>
#include <hip/hip_bf16.h>

#define T_DIM 8192
#define H_DIM 2048
#define F_DIM 5632

typedef __attribute__((ext_vector_type(4))) float f32x4;
typedef __attribute__((ext_vector_type(8))) short bf16x8;

static __device__ __forceinline__ void gload16(const void* g, void* l) {
    __builtin_amdgcn_global_load_lds(
        (const __attribute__((address_space(1))) void*)g,
        (__attribute__((address_space(3))) void*)l,
        16, 0, 0);
}

static __device__ __forceinline__ unsigned short f2bf(float f) {
    unsigned int u = __float_as_uint(f);
    u += 0x7fffu + ((u >> 16) & 1u);
    return (unsigned short)(u >> 16);
}

// ---- f32 -> bf16 conversion: X ----
__global__ __launch_bounds__(256)
void cvt_x(const float* __restrict__ src, unsigned short* __restrict__ dst, long n)
{
    const long stride = (long)gridDim.x * blockDim.x;
    for (long i = (long)blockIdx.x * blockDim.x + threadIdx.x; i * 4 < n; i += stride) {
        const float4 v = *(const float4*)(src + i * 4);
        ushort4 o;
        o.x = f2bf(v.x); o.y = f2bf(v.y); o.z = f2bf(v.z); o.w = f2bf(v.w);
        *(ushort4*)(dst + i * 4) = o;
    }
}

// ---- f32 -> bf16 weight conversion (r10-verified 16-row interleave).
// W1 row r -> R = (r>>4)*32 + (r&15);  W2 row r -> R + 16.  W3 linear.
__global__ __launch_bounds__(256)
void cvt_w(const float* __restrict__ w1, const float* __restrict__ w2,
           const float* __restrict__ w3, const int* __restrict__ eidx,
           unsigned short* __restrict__ W12, unsigned short* __restrict__ W3b)
{
    const long seg = (long)F_DIM * H_DIM;
    const long e   = (long)(*eidx);
    const long nchunks = 3 * seg / 4;
    const long stride = (long)gridDim.x * blockDim.x;
    for (long i = (long)blockIdx.x * blockDim.x + threadIdx.x; i < nchunks; i += stride) {
        const long t = i * 4;
        const int  s = (int)(t / seg);
        const long o = t - (long)s * seg;
        const float4 v = *(const float4*)((s == 0 ? w1 : s == 1 ? w2 : w3) + e * seg + o);
        ushort4 ov;
        ov.x = f2bf(v.x); ov.y = f2bf(v.y); ov.z = f2bf(v.z); ov.w = f2bf(v.w);
        if (s == 2) {
            *(ushort4*)(W3b + o) = ov;
        } else {
            const long r   = o >> 11;
            const long col = o & 2047;
            const long R   = (r >> 4) * 32 + (r & 15) + (s == 1 ? 16 : 0);
            *(ushort4*)(W12 + R * 2048 + col) = ov;
        }
    }
}

// ---- staging helpers (XOR-swizzled source, linear LDS dest; rule #21) ----
// 512-thread version: one call = 2 issues = 128 rows (rows i0*64 .. i0*64+128)
static __device__ __forceinline__ void stage_half(const unsigned short* __restrict__ g,
                                                  long grow0, long ldk, long kb,
                                                  unsigned short* l, int t, int i0)
{
    const int r  = t >> 3;
    const int cc = ((t & 7) ^ (r & 7)) << 3;
    #pragma unroll
    for (int ii = i0; ii < i0 + 2; ++ii)
        gload16(g + (grow0 + ii * 64 + r) * ldk + kb + cc,
                l + ii * 4096 + t * 8);
}

// 1024-thread version: one call = 1 issue = 128 rows (t = 0..1023)
static __device__ __forceinline__ void stage_q(const unsigned short* __restrict__ g,
                                               long grow0, long ldk, long kb,
                                               unsigned short* l, int t)
{
    const int r  = t >> 3;                       // 0..127
    const int cc = ((t & 7) ^ (r & 7)) << 3;     // inverse-swizzled source chunk
    gload16(g + (grow0 + r) * ldk + kb + cc, l + t * 8);
}

static __device__ __forceinline__ bf16x8 ldsfrag(const unsigned short* base,
                                                 int row, int kk, int q)
{
    return *(const bf16x8*)(base + row * 64 + (((kk * 4 + q) ^ (row & 7)) << 3));
}

// ---- FC1: 1024 threads (16 waves), tile 256M x 128out (B = 256 W12 rows).
// LDS 128 KB: A dbuf 2x32KB + B dbuf 2x32KB -> 1 block/CU, 4 waves/SIMD
// (same wave occupancy as r10's 2x8, half the staged bytes per MFMA).
// Waves 2M x 8N; per wave Mf=8, Nf=2 (gate,up), acc[8][2]=64 regs (r10 shape).
// 2 barriers/iter: B1 = staged-visibility, B2 = reads-retired before next
// iter's gload_lds overwrites (MFMA issue implies lgkm-complete of its reads).
__global__ __launch_bounds__(1024, 4)
void gemm_fc1(const unsigned short* __restrict__ X,
              const unsigned short* __restrict__ W12,
              unsigned short* __restrict__ Hout)
{
    constexpr int NK = H_DIM / 64;   // 32

    __shared__ __align__(16) unsigned short sAll[65536];  // 128 KiB

    const int tid  = threadIdx.x;
    const int lane = tid & 63;
    const int wid  = tid >> 6;       // 0..15
    const int wm   = wid >> 3;       // 0..1 : 128-row M halves
    const int wn   = wid & 7;        // 0..7 : 16-col N groups
    const int q    = lane >> 4;
    const int lr   = lane & 15;

    // grid 1408 = 8 XCD x 176; per XCD: bn-major quads of bm
    const int bid = blockIdx.x;
    const int x   = bid & 7;
    const int ii  = bid >> 3;        // 0..175
    const int bn  = ii >> 2;         // 0..43
    const int bm  = x * 4 + (ii & 3);// 0..31

    const long arow0 = (long)bm * 256;
    const long brow0 = (long)bn * 256;   // W12 rows (256 rows = 128 out-cols)

    unsigned short* bufA = sAll;               // 2 x 16384 elems
    unsigned short* bufB = sAll + 32768;       // 2 x 16384 elems

    f32x4 acc[8][2] = {};

    // prologue: A(0), B(0) -> buf0
    stage_q(X,   arow0,       H_DIM, 0, bufA,        tid);
    stage_q(X,   arow0 + 128, H_DIM, 0, bufA + 8192, tid);
    stage_q(W12, brow0,       H_DIM, 0, bufB,        tid);
    stage_q(W12, brow0 + 128, H_DIM, 0, bufB + 8192, tid);

    for (int j = 0; j < NK; ++j) {
        unsigned short* la = bufA + (j & 1) * 16384;
        unsigned short* lb = bufB + (j & 1) * 16384;

        if (j + 1 < NK) {
            unsigned short* na = bufA + ((j + 1) & 1) * 16384;
            unsigned short* nb = bufB + ((j + 1) & 1) * 16384;
            const long kbn = (long)(j + 1) * 64;
            stage_q(X,   arow0,       H_DIM, kbn, na,        tid);
            stage_q(X,   arow0 + 128, H_DIM, kbn, na + 8192, tid);
            stage_q(W12, brow0,       H_DIM, kbn, nb,        tid);
            stage_q(W12, brow0 + 128, H_DIM, kbn, nb + 8192, tid);
            // queue: [A(j):2, B(j):2, A(j+1):2, B(j+1):2] -> keep 4 newest
            asm volatile("s_waitcnt vmcnt(4)" ::: "memory");
        } else {
            asm volatile("s_waitcnt vmcnt(0)" ::: "memory");
        }
        __builtin_amdgcn_s_barrier();        // B1: A(j),B(j) visible

        // B frags: wave-local 32 W12 rows = 16 gate + 16 up (out-cols wn*16..)
        bf16x8 bf[2][2];
        #pragma unroll
        for (int nb_ = 0; nb_ < 2; ++nb_)
            #pragma unroll
            for (int kk = 0; kk < 2; ++kk)
                bf[nb_][kk] = ldsfrag(lb, wn * 32 + nb_ * 16 + lr, kk, q);

        // group 0: mi 0..3
        {
            bf16x8 af[4][2];
            #pragma unroll
            for (int mi = 0; mi < 4; ++mi)
                #pragma unroll
                for (int kk = 0; kk < 2; ++kk)
                    af[mi][kk] = ldsfrag(la, wm * 128 + mi * 16 + lr, kk, q);
            __builtin_amdgcn_s_setprio(1);
            #pragma unroll
            for (int mi = 0; mi < 4; ++mi)
                #pragma unroll
                for (int nb_ = 0; nb_ < 2; ++nb_)
                    #pragma unroll
                    for (int kk = 0; kk < 2; ++kk)
                        acc[mi][nb_] = __builtin_amdgcn_mfma_f32_16x16x32_bf16(
                            af[mi][kk], bf[nb_][kk], acc[mi][nb_], 0, 0, 0);
            __builtin_amdgcn_s_setprio(0);
        }
        // group 1: mi 4..7
        {
            bf16x8 af[4][2];
            #pragma unroll
            for (int mi = 0; mi < 4; ++mi)
                #pragma unroll
                for (int kk = 0; kk < 2; ++kk)
                    af[mi][kk] = ldsfrag(la, wm * 128 + (mi + 4) * 16 + lr, kk, q);
            __builtin_amdgcn_s_setprio(1);
            #pragma unroll
            for (int mi = 0; mi < 4; ++mi)
                #pragma unroll
                for (int nb_ = 0; nb_ < 2; ++nb_)
                    #pragma unroll
                    for (int kk = 0; kk < 2; ++kk)
                        acc[mi + 4][nb_] = __builtin_amdgcn_mfma_f32_16x16x32_bf16(
                            af[mi][kk], bf[nb_][kk], acc[mi + 4][nb_], 0, 0, 0);
            __builtin_amdgcn_s_setprio(0);
        }
        __builtin_amdgcn_s_barrier();        // B2: all reads retired -> next overwrite safe
    }

    // terminal epilogue: h = silu(gate)*up
    const long orow = (long)bm * 256 + wm * 128;
    const long ocol = (long)bn * 128 + wn * 16 + lr;
    #pragma unroll
    for (int mi = 0; mi < 8; ++mi)
        #pragma unroll
        for (int r = 0; r < 4; ++r) {
            const float g = acc[mi][0][r];
            const float u = acc[mi][1][r];
            const float h = __fdividef(g, 1.0f + __expf(-g)) * u;
            Hout[(orow + mi * 16 + q * 4 + r) * (long)F_DIM + ocol] = f2bf(h);
        }
}

// ---- GEMM2 phase (unchanged proven template) ----
#define PHASE_BODY(p, STAGE_STMT)                                              \
    {                                                                          \
        bf16x8 af[2][2];                                                       \
        _Pragma("unroll")                                                      \
        for (int l_ = 0; l_ < 2; ++l_)                                         \
            _Pragma("unroll")                                                  \
            for (int kk = 0; kk < 2; ++kk)                                     \
                af[l_][kk] = ldsfrag(la, wm * 128 + (p) * 32 + l_ * 16 + lr, kk, q); \
        STAGE_STMT;                                                            \
        __builtin_amdgcn_s_barrier();                                          \
        __builtin_amdgcn_s_setprio(1);                                         \
        _Pragma("unroll")                                                      \
        for (int l_ = 0; l_ < 2; ++l_)                                         \
            _Pragma("unroll")                                                  \
            for (int ni = 0; ni < 4; ++ni)                                     \
                _Pragma("unroll")                                              \
                for (int kk = 0; kk < 2; ++kk)                                 \
                    acc[(p) * 2 + l_][ni] = __builtin_amdgcn_mfma_f32_16x16x32_bf16( \
                        af[l_][kk], bf[ni][kk], acc[(p) * 2 + l_][ni], 0, 0, 0);     \
        __builtin_amdgcn_s_setprio(0);                                         \
        __builtin_amdgcn_s_barrier();                                          \
    }

// ---- GEMM2: Out = H * W3^T.  H [T,F] bf16, W3 [H,F] bf16, Out [T,H] f32 ----
__global__ __launch_bounds__(512, 2)
void gemm_out(const unsigned short* __restrict__ A,
              const unsigned short* __restrict__ B,
              float* __restrict__ Out)
{
    constexpr int NK  = F_DIM / 64;   // 88
    constexpr int NBN = H_DIM / 256;  // 8

    __shared__ __align__(16) unsigned short sAll[4 * 16384];

    const int tid  = threadIdx.x;
    const int lane = tid & 63;
    const int wid  = tid >> 6;
    const int wm   = wid >> 2;
    const int wn   = wid & 3;
    const int q    = lane >> 4;
    const int lr   = lane & 15;

    const int nwg = gridDim.x;                 // 256
    const int bid = blockIdx.x;
    const int cpx = nwg >> 3;
    const int swz = (bid & 7) * cpx + (bid >> 3);
    const int bm  = swz / NBN;
    const int bn  = swz % NBN;

    const long arow0 = (long)bm * 256;
    const long brow0 = (long)bn * 256;

    f32x4 acc[8][4] = {};

    stage_half(A, arow0, F_DIM, 0,  sAll,          tid, 0);
    stage_half(A, arow0, F_DIM, 0,  sAll,          tid, 2);
    stage_half(B, brow0, F_DIM, 0,  sAll + 16384,  tid, 0);
    stage_half(B, brow0, F_DIM, 0,  sAll + 16384,  tid, 2);
    stage_half(B, brow0, F_DIM, 64, sAll + 49152,  tid, 0);
    stage_half(B, brow0, F_DIM, 64, sAll + 49152,  tid, 2);

    for (int j = 0; j < NK; ++j) {
        unsigned short* la = sAll + (j & 1) * 32768;
        unsigned short* lb = la + 16384;

        if (j + 1 < NK) {
            unsigned short* na = sAll + ((j + 1) & 1) * 32768;
            stage_half(A, arow0, F_DIM, (long)(j + 1) * 64, na, tid, 0);
            stage_half(A, arow0, F_DIM, (long)(j + 1) * 64, na, tid, 2);
            asm volatile("s_waitcnt vmcnt(8)" ::: "memory");
        } else {
            asm volatile("s_waitcnt vmcnt(0)" ::: "memory");
        }
        __builtin_amdgcn_s_barrier();

        bf16x8 bf[4][2];
        #pragma unroll
        for (int ni = 0; ni < 4; ++ni)
            #pragma unroll
            for (int kk = 0; kk < 2; ++kk)
                bf[ni][kk] = ldsfrag(lb, wn * 64 + ni * 16 + lr, kk, q);

        PHASE_BODY(0, {})
        PHASE_BODY(1, { if (j + 2 < NK) stage_half(B, brow0, F_DIM, (long)(j + 2) * 64, lb, tid, 0); })
        PHASE_BODY(2, { if (j + 2 < NK) stage_half(B, brow0, F_DIM, (long)(j + 2) * 64, lb, tid, 2); })
        PHASE_BODY(3, {})
    }

    const long orow = (long)bm * 256 + wm * 128;
    const long ocol = (long)bn * 256 + wn * 64;
    #pragma unroll
    for (int mi = 0; mi < 8; ++mi)
        #pragma unroll
        for (int ni = 0; ni < 4; ++ni)
            #pragma unroll
            for (int r = 0; r < 4; ++r)
                Out[(orow + mi * 16 + q * 4 + r) * (long)H_DIM + (ocol + ni * 16 + lr)]
                    = acc[mi][ni][r];
}

extern "C" void kernel_launch(void* const* d_in, const int* in_sizes, int n_in,
                              void* d_out, int out_size, void* d_ws, size_t ws_size,
                              hipStream_t stream)
{
    const int*   eidx = (const int*)d_in[0];
    const float* x    = (const float*)d_in[1];
    const float* w1   = (const float*)d_in[2];
    const float* w2   = (const float*)d_in[3];
    const float* w3   = (const float*)d_in[4];
    float* out = (float*)d_out;

    const size_t SZ_X = (size_t)T_DIM * H_DIM;
    const size_t SZ_W = (size_t)F_DIM * H_DIM;

    unsigned short* Xb  = (unsigned short*)d_ws;
    unsigned short* W12 = Xb  + SZ_X;            // [11264 x 2048] interleaved
    unsigned short* W3b = W12 + 2 * SZ_W;
    unsigned short* Hb  = W3b + SZ_W;

    cvt_x<<<2048, 256, 0, stream>>>(x, Xb, (long)SZ_X);
    cvt_w<<<2048, 256, 0, stream>>>(w1, w2, w3, eidx, W12, W3b);

    gemm_fc1<<<1408, 1024, 0, stream>>>(Xb, W12, Hb);
    gemm_out<<<(T_DIM / 256) * (H_DIM / 256), 512, 0, stream>>>(Hb, W3b, out);
}

// Round 15
// 532.890 us; speedup vs baseline: 1.2346x; 1.0612x over previous
//
#include <hip/hip_runtime.h>
#include <hip/hip_bf16.h>

#define T_DIM 8192
#define H_DIM 2048
#define F_DIM 5632

typedef __attribute__((ext_vector_type(4))) float f32x4;
typedef __attribute__((ext_vector_type(8))) short bf16x8;

static __device__ __forceinline__ void gload16(const void* g, void* l) {
    __builtin_amdgcn_global_load_lds(
        (const __attribute__((address_space(1))) void*)g,
        (__attribute__((address_space(3))) void*)l,
        16, 0, 0);
}

static __device__ __forceinline__ unsigned short f2bf(float f) {
    unsigned int u = __float_as_uint(f);
    u += 0x7fffu + ((u >> 16) & 1u);
    return (unsigned short)(u >> 16);
}

// ---- f32 -> bf16 conversion: X ----
__global__ __launch_bounds__(256)
void cvt_x(const float* __restrict__ src, unsigned short* __restrict__ dst, long n)
{
    const long stride = (long)gridDim.x * blockDim.x;
    for (long i = (long)blockIdx.x * blockDim.x + threadIdx.x; i * 4 < n; i += stride) {
        const float4 v = *(const float4*)(src + i * 4);
        ushort4 o;
        o.x = f2bf(v.x); o.y = f2bf(v.y); o.z = f2bf(v.z); o.w = f2bf(v.w);
        *(ushort4*)(dst + i * 4) = o;
    }
}

// ---- f32 -> bf16 weight conversion.
// W1/W2 interleaved into W12[11264 x 2048] at 16-row granularity:
//   W1 row r -> R = (r>>4)*32 + (r&15);  W2 row r -> R + 16
// so B-tile rows bn*128..+128 = out-cols bn*64..+64, and wave wn's 32 rows
// (wn*32..) are [16 gate | 16 up] for cols bn*64+wn*16..+16.
// W3 converted linearly.
__global__ __launch_bounds__(256)
void cvt_w(const float* __restrict__ w1, const float* __restrict__ w2,
           const float* __restrict__ w3, const int* __restrict__ eidx,
           unsigned short* __restrict__ W12, unsigned short* __restrict__ W3b)
{
    const long seg = (long)F_DIM * H_DIM;
    const long e   = (long)(*eidx);
    const long nchunks = 3 * seg / 4;
    const long stride = (long)gridDim.x * blockDim.x;
    for (long i = (long)blockIdx.x * blockDim.x + threadIdx.x; i < nchunks; i += stride) {
        const long t = i * 4;
        const int  s = (int)(t / seg);
        const long o = t - (long)s * seg;
        const float4 v = *(const float4*)((s == 0 ? w1 : s == 1 ? w2 : w3) + e * seg + o);
        ushort4 ov;
        ov.x = f2bf(v.x); ov.y = f2bf(v.y); ov.z = f2bf(v.z); ov.w = f2bf(v.w);
        if (s == 2) {
            *(ushort4*)(W3b + o) = ov;
        } else {
            const long r   = o >> 11;
            const long col = o & 2047;
            const long R   = (r >> 4) * 32 + (r & 15) + (s == 1 ? 16 : 0);
            *(ushort4*)(W12 + R * 2048 + col) = ov;
        }
    }
}

// ---- staging / frag helpers (XOR-swizzled, rule #21) ----
static __device__ __forceinline__ void stage_half(const unsigned short* __restrict__ g,
                                                  long grow0, long ldk, long kb,
                                                  unsigned short* l, int t, int i0)
{
    const int r  = t >> 3;
    const int cc = ((t & 7) ^ (r & 7)) << 3;   // inverse-swizzled source column
    #pragma unroll
    for (int ii = i0; ii < i0 + 2; ++ii)
        gload16(g + (grow0 + ii * 64 + r) * ldk + kb + cc,
                l + ii * 4096 + t * 8);
}

static __device__ __forceinline__ bf16x8 ldsfrag(const unsigned short* base,
                                                 int row, int kk, int q)
{
    return *(const bf16x8*)(base + row * 64 + (((kk * 4 + q) ^ (row & 7)) << 3));
}

// ---- FC1 phase: 8 MFMA (2 M-frags x {gate,up} x 2 kk) ----
#define FC1_PHASE(p, STAGE_STMT)                                               \
    {                                                                          \
        bf16x8 af[2][2];                                                       \
        _Pragma("unroll")                                                      \
        for (int l_ = 0; l_ < 2; ++l_)                                         \
            _Pragma("unroll")                                                  \
            for (int kk = 0; kk < 2; ++kk)                                     \
                af[l_][kk] = ldsfrag(la, wm * 128 + (p) * 32 + l_ * 16 + lr, kk, q); \
        STAGE_STMT;                                                            \
        __builtin_amdgcn_s_barrier();                                          \
        __builtin_amdgcn_s_setprio(1);                                         \
        _Pragma("unroll")                                                      \
        for (int l_ = 0; l_ < 2; ++l_)                                         \
            _Pragma("unroll")                                                  \
            for (int nb = 0; nb < 2; ++nb)                                     \
                _Pragma("unroll")                                              \
                for (int kk = 0; kk < 2; ++kk)                                 \
                    acc[(p) * 2 + l_][nb] = __builtin_amdgcn_mfma_f32_16x16x32_bf16( \
                        af[l_][kk], bf[nb][kk], acc[(p) * 2 + l_][nb], 0, 0, 0);     \
        __builtin_amdgcn_s_setprio(0);                                         \
        __builtin_amdgcn_s_barrier();                                          \
    }

// ---- FC1: tile 256 M-rows x 64 out-cols (B-tile 128 interleaved rows).
// LDS 80 KB (A dbuf 2x32KB + B single 16KB) -> 2 blocks/CU. acc[mi][0]=gate,
// acc[mi][1]=up, same cols; terminal epilogue h = silu(g)*u.
// 2 blocks/CU = two independent barrier domains -- the confirmed +17% (r10).
__global__ __launch_bounds__(512, 4)
void gemm_fc1(const unsigned short* __restrict__ X,
              const unsigned short* __restrict__ W12,
              unsigned short* __restrict__ Hout)
{
    constexpr int NK = H_DIM / 64;   // 32

    __shared__ __align__(16) unsigned short sAll[40960];  // 80 KiB

    const int tid  = threadIdx.x;
    const int lane = tid & 63;
    const int wid  = tid >> 6;
    const int wm   = wid >> 2;       // 0..1 : M halves
    const int wn   = wid & 3;        // 0..3 : 16-col groups
    const int q    = lane >> 4;
    const int lr   = lane & 15;

    // grid 2816 = 8 XCD x 352; per XCD: bn-major quads of bm
    const int bid = blockIdx.x;
    const int x   = bid & 7;
    const int ii  = bid >> 3;        // 0..351
    const int bn  = ii >> 2;         // 0..87
    const int bm  = x * 4 + (ii & 3);// 0..31

    const long arow0 = (long)bm * 256;
    const long brow0 = (long)bn * 128;   // W12 rows

    unsigned short* sB = sAll + 32768;

    f32x4 acc[8][2] = {};

    // prologue: A(0) -> bufA0 ; B(0) -> sB
    stage_half(X,   arow0, H_DIM, 0, sAll, tid, 0);
    stage_half(X,   arow0, H_DIM, 0, sAll, tid, 2);
    stage_half(W12, brow0, H_DIM, 0, sB,   tid, 0);   // 128 rows, 16 KB

    for (int j = 0; j < NK; ++j) {
        unsigned short* la = sAll + (j & 1) * 16384;

        if (j + 1 < NK) {
            unsigned short* na = sAll + ((j + 1) & 1) * 16384;
            stage_half(X, arow0, H_DIM, (long)(j + 1) * 64, na, tid, 0);
            stage_half(X, arow0, H_DIM, (long)(j + 1) * 64, na, tid, 2);
            // outstanding: [A(j):4, B(j):2, A(j+1):4] -> keep 4 newest
            asm volatile("s_waitcnt vmcnt(4)" ::: "memory");
        } else {
            asm volatile("s_waitcnt vmcnt(0)" ::: "memory");
        }
        __builtin_amdgcn_s_barrier();

        // hoist this iter's B frags (wave-local 32 rows = 16 gate + 16 up)
        bf16x8 bf[2][2];
        #pragma unroll
        for (int nb = 0; nb < 2; ++nb)
            #pragma unroll
            for (int kk = 0; kk < 2; ++kk)
                bf[nb][kk] = ldsfrag(sB, wn * 32 + nb * 16 + lr, kk, q);

        FC1_PHASE(0, {})
        FC1_PHASE(1, { if (j + 1 < NK)
                           stage_half(W12, brow0, H_DIM, (long)(j + 1) * 64, sB, tid, 0); })
        FC1_PHASE(2, {})
        FC1_PHASE(3, {})
    }

    // terminal epilogue
    const long orow = (long)bm * 256 + wm * 128;
    const long ocol = (long)bn * 64 + wn * 16 + lr;
    #pragma unroll
    for (int mi = 0; mi < 8; ++mi)
        #pragma unroll
        for (int r = 0; r < 4; ++r) {
            const float g = acc[mi][0][r];
            const float u = acc[mi][1][r];
            const float h = __fdividef(g, 1.0f + __expf(-g)) * u;
            Hout[(orow + mi * 16 + q * 4 + r) * (long)F_DIM + ocol] = f2bf(h);
        }
}

// ---- GEMM2 phase (unchanged proven template) ----
#define PHASE_BODY(p, STAGE_STMT)                                              \
    {                                                                          \
        bf16x8 af[2][2];                                                       \
        _Pragma("unroll")                                                      \
        for (int l_ = 0; l_ < 2; ++l_)                                         \
            _Pragma("unroll")                                                  \
            for (int kk = 0; kk < 2; ++kk)                                     \
                af[l_][kk] = ldsfrag(la, wm * 128 + (p) * 32 + l_ * 16 + lr, kk, q); \
        STAGE_STMT;                                                            \
        __builtin_amdgcn_s_barrier();                                          \
        __builtin_amdgcn_s_setprio(1);                                         \
        _Pragma("unroll")                                                      \
        for (int l_ = 0; l_ < 2; ++l_)                                         \
            _Pragma("unroll")                                                  \
            for (int ni = 0; ni < 4; ++ni)                                     \
                _Pragma("unroll")                                              \
                for (int kk = 0; kk < 2; ++kk)                                 \
                    acc[(p) * 2 + l_][ni] = __builtin_amdgcn_mfma_f32_16x16x32_bf16( \
                        af[l_][kk], bf[ni][kk], acc[(p) * 2 + l_][ni], 0, 0, 0);     \
        __builtin_amdgcn_s_setprio(0);                                         \
        __builtin_amdgcn_s_barrier();                                          \
    }

// ---- GEMM2: Out = H * W3^T.  H [T,F] bf16, W3 [H,F] bf16, Out [T,H] f32 ----
__global__ __launch_bounds__(512, 2)
void gemm_out(const unsigned short* __restrict__ A,
              const unsigned short* __restrict__ B,
              float* __restrict__ Out)
{
    constexpr int NK  = F_DIM / 64;   // 88
    constexpr int NBN = H_DIM / 256;  // 8

    __shared__ __align__(16) unsigned short sAll[4 * 16384];

    const int tid  = threadIdx.x;
    const int lane = tid & 63;
    const int wid  = tid >> 6;
    const int wm   = wid >> 2;
    const int wn   = wid & 3;
    const int q    = lane >> 4;
    const int lr   = lane & 15;

    const int nwg = gridDim.x;                 // 256
    const int bid = blockIdx.x;
    const int cpx = nwg >> 3;
    const int swz = (bid & 7) * cpx + (bid >> 3);
    const int bm  = swz / NBN;
    const int bn  = swz % NBN;

    const long arow0 = (long)bm * 256;
    const long brow0 = (long)bn * 256;

    f32x4 acc[8][4] = {};

    stage_half(A, arow0, F_DIM, 0,  sAll,          tid, 0);
    stage_half(A, arow0, F_DIM, 0,  sAll,          tid, 2);
    stage_half(B, brow0, F_DIM, 0,  sAll + 16384,  tid, 0);
    stage_half(B, brow0, F_DIM, 0,  sAll + 16384,  tid, 2);
    stage_half(B, brow0, F_DIM, 64, sAll + 49152,  tid, 0);
    stage_half(B, brow0, F_DIM, 64, sAll + 49152,  tid, 2);

    for (int j = 0; j < NK; ++j) {
        unsigned short* la = sAll + (j & 1) * 32768;
        unsigned short* lb = la + 16384;

        if (j + 1 < NK) {
            unsigned short* na = sAll + ((j + 1) & 1) * 32768;
            stage_half(A, arow0, F_DIM, (long)(j + 1) * 64, na, tid, 0);
            stage_half(A, arow0, F_DIM, (long)(j + 1) * 64, na, tid, 2);
            asm volatile("s_waitcnt vmcnt(8)" ::: "memory");
        } else {
            asm volatile("s_waitcnt vmcnt(0)" ::: "memory");
        }
        __builtin_amdgcn_s_barrier();

        bf16x8 bf[4][2];
        #pragma unroll
        for (int ni = 0; ni < 4; ++ni)
            #pragma unroll
            for (int kk = 0; kk < 2; ++kk)
                bf[ni][kk] = ldsfrag(lb, wn * 64 + ni * 16 + lr, kk, q);

        PHASE_BODY(0, {})
        PHASE_BODY(1, { if (j + 2 < NK) stage_half(B, brow0, F_DIM, (long)(j + 2) * 64, lb, tid, 0); })
        PHASE_BODY(2, { if (j + 2 < NK) stage_half(B, brow0, F_DIM, (long)(j + 2) * 64, lb, tid, 2); })
        PHASE_BODY(3, {})
    }

    const long orow = (long)bm * 256 + wm * 128;
    const long ocol = (long)bn * 256 + wn * 64;
    #pragma unroll
    for (int mi = 0; mi < 8; ++mi)
        #pragma unroll
        for (int ni = 0; ni < 4; ++ni)
            #pragma unroll
            for (int r = 0; r < 4; ++r)
                Out[(orow + mi * 16 + q * 4 + r) * (long)H_DIM + (ocol + ni * 16 + lr)]
                    = acc[mi][ni][r];
}

extern "C" void kernel_launch(void* const* d_in, const int* in_sizes, int n_in,
                              void* d_out, int out_size, void* d_ws, size_t ws_size,
                              hipStream_t stream)
{
    const int*   eidx = (const int*)d_in[0];
    const float* x    = (const float*)d_in[1];
    const float* w1   = (const float*)d_in[2];
    const float* w2   = (const float*)d_in[3];
    const float* w3   = (const float*)d_in[4];
    float* out = (float*)d_out;

    const size_t SZ_X = (size_t)T_DIM * H_DIM;
    const size_t SZ_W = (size_t)F_DIM * H_DIM;

    unsigned short* Xb  = (unsigned short*)d_ws;
    unsigned short* W12 = Xb  + SZ_X;            // [11264 x 2048] interleaved
    unsigned short* W3b = W12 + 2 * SZ_W;
    unsigned short* Hb  = W3b + SZ_W;

    cvt_x<<<2048, 256, 0, stream>>>(x, Xb, (long)SZ_X);
    cvt_w<<<2048, 256, 0, stream>>>(w1, w2, w3, eidx, W12, W3b);

    gemm_fc1<<<2816, 512, 0, stream>>>(Xb, W12, Hb);
    gemm_out<<<(T_DIM / 256) * (H_DIM / 256), 512, 0, stream>>>(Hb, W3b, out);
}